// Round 6
// baseline (190.584 us; speedup 1.0000x reference)
//
#include <hip/hip_runtime.h>

#define NN 100000
#define NE 600000
#define DD 128
#define BN_EPS 1e-5f
#define NB1 391                 // (NN+255)/256 scan blocks
#define NCV 12500               // convert blocks (8 rows each)
#define NFB 2344                // fill blocks
#define NBLK 782                // gather blocks (512 thr, 8 waves, 128 nodes each)

typedef __attribute__((ext_vector_type(8))) short bf16x8;
typedef __attribute__((ext_vector_type(4))) float f32x4;

static __device__ __forceinline__ unsigned short f2bf(float f) {
    unsigned u = __float_as_uint(f);
    unsigned r = (u + 0x7FFFu + ((u >> 16) & 1u)) >> 16;   // RNE
    return (unsigned short)r;
}
static __device__ __forceinline__ float bflo(unsigned v) { return __uint_as_float(v << 16); }
static __device__ __forceinline__ float bfhi(unsigned v) { return __uint_as_float(v & 0xFFFF0000u); }

// ---------------------------------------------------------------- init: cnt=0, stats=0, W->Wt bf16 transpose
__global__ __launch_bounds__(256) void k_init(int* __restrict__ cnt,
                                              float* __restrict__ stats,
                                              const float* __restrict__ W,
                                              unsigned short* __restrict__ Wt) {
    int i = blockIdx.x * 256 + threadIdx.x;
    if (i < NN) cnt[i] = 0;
    if (i < 256) stats[i] = 0.0f;
    if (i < DD * DD) {
        int k = i >> 7, c = i & 127;
        Wt[c * DD + k] = f2bf(W[i]);   // Wt[col][k]
    }
}

// ---------------------------------------------------------------- count incoming edges
__global__ __launch_bounds__(256) void k_count(const int* __restrict__ dst,
                                               int* __restrict__ cnt) {
    int e = blockIdx.x * 256 + threadIdx.x;
    if (e < NE) atomicAdd(&cnt[dst[e]], 1);
}

// ---------------------------------------------------------------- scan pass 1 over (cnt[i]+1)  [self edge included]
__global__ __launch_bounds__(256) void k_scan1(const int* __restrict__ cnt,
                                               int* __restrict__ offs,
                                               int* __restrict__ bsum) {
    __shared__ int tmp[256];
    int tid = threadIdx.x;
    int i = blockIdx.x * 256 + tid;
    int v = (i < NN) ? (cnt[i] + 1) : 0;
    tmp[tid] = v;
    __syncthreads();
    #pragma unroll
    for (int d = 1; d < 256; d <<= 1) {
        int t = (tid >= d) ? tmp[tid - d] : 0;
        __syncthreads();
        tmp[tid] += t;
        __syncthreads();
    }
    if (i < NN) offs[i] = tmp[tid] - v;
    if (tid == 255) bsum[blockIdx.x] = tmp[255];
}

// ---------------------------------------------------------------- scan pass 2 (1 block)
__global__ __launch_bounds__(512) void k_scan2(int* __restrict__ bsum) {
    __shared__ int tmp[512];
    int tid = threadIdx.x;
    int v = (tid < NB1) ? bsum[tid] : 0;
    tmp[tid] = v;
    __syncthreads();
    #pragma unroll
    for (int d = 1; d < 512; d <<= 1) {
        int t = (tid >= d) ? tmp[tid - d] : 0;
        __syncthreads();
        tmp[tid] += t;
        __syncthreads();
    }
    if (tid < NB1) bsum[tid] = tmp[tid] - v;
}

// ---------------------------------------------------------------- scan pass 3: finalize offs, self edge, cursor, dinv
__global__ __launch_bounds__(256) void k_scan3(int* __restrict__ offs,
                                               const int* __restrict__ bsum,
                                               const int* __restrict__ cnt,
                                               int* __restrict__ cur,
                                               float* __restrict__ dinv,
                                               int* __restrict__ srcs) {
    int i = blockIdx.x * 256 + threadIdx.x;
    if (i < NN) {
        int o = offs[i] + bsum[blockIdx.x];
        offs[i] = o;
        dinv[i] = rsqrtf((float)(cnt[i] + 1));
        srcs[o] = i;                     // self edge at slot 0
        cur[i]  = o + 1;
        if (i == 0) offs[NN] = NE + NN;  // sentinel
    }
}

// ---------------------------------------------------------------- merged: xn = bf16(x*dinv)  ||  CSR fill (src only)
__global__ __launch_bounds__(256) void k_cvfill(const float* __restrict__ x,
                                                const float* __restrict__ dinv,
                                                unsigned short* __restrict__ xn,
                                                const int* __restrict__ src,
                                                const int* __restrict__ dst,
                                                int* __restrict__ cur,
                                                int* __restrict__ srcs) {
    int bid = blockIdx.x;
    if (bid < NCV) {
        int r  = bid * 8 + (threadIdx.x >> 5);
        int c4 = threadIdx.x & 31;
        float di = dinv[r];
        float4 v = ((const float4*)x)[(size_t)r * 32 + c4];
        unsigned p0 = ((unsigned)f2bf(v.y * di) << 16) | f2bf(v.x * di);
        unsigned p1 = ((unsigned)f2bf(v.w * di) << 16) | f2bf(v.z * di);
        ((uint2*)xn)[(size_t)r * 32 + c4] = make_uint2(p0, p1);
    } else {
        int e = (bid - NCV) * 256 + threadIdx.x;
        if (e < NE) {
            int s = src[e], t = dst[e];
            int slot = atomicAdd(&cur[t], 1);
            srcs[slot] = s;
        }
    }
}

// ---------------------------------------------------------------- fused gather + MFMA-GEMM + bias + stats
// 512 threads = 8 waves; wave owns 16 consecutive nodes.
// Phase 1: unweighted sum of xn[src] rows (f32), scale by dinv[node], pack bf16 -> swizzled LDS.
// Phase 2: 16x16x32 MFMA vs LDS-staged W; epilogue: +bias, stats, f32 stores.
__global__ __launch_bounds__(512) void k_gather(const int* __restrict__ offs,
                                                const int* __restrict__ srcs,
                                                const unsigned short* __restrict__ xn,
                                                const float* __restrict__ dinv,
                                                const float* __restrict__ b,
                                                const unsigned short* __restrict__ Wt,
                                                float* __restrict__ out,
                                                float* __restrict__ partial) {
    // swizzle rule (both write & read): byte(row, colbyte) = row*256 + (colbyte ^ ((row&7)<<4))
    __shared__ uint4 Wl4[2048];        // 32 KB: W cols as rows, bf16, swizzled
    __shared__ uint4 agg4[8][256];     // 8 waves x 4 KB: 16 aggregated rows, bf16, swizzled
    __shared__ float lsum[8][128], lss[8][128];

    const int tid  = threadIdx.x;
    const int wid  = tid >> 6;
    const int lane = tid & 63;
    const int lm   = lane & 15;        // row-slice / A-row / B-col
    const int lk   = lane >> 4;        // edge group / k-chunk
    char* Wl  = (char*)Wl4;
    char* agp = (char*)agg4[wid];

    // stage W (Wt rows = W columns) into swizzled LDS, coalesced uint4
    #pragma unroll
    for (int it = 0; it < 4; ++it) {
        int chunk = it * 512 + tid;            // 0..2047
        int row = chunk >> 4, c16 = chunk & 15;
        uint4 v = *(const uint4*)(Wt + row * DD + c16 * 8);
        *(uint4*)(Wl + row * 256 + (((c16 ^ (row & 7)) << 4))) = v;
    }
    float bb[8];
    #pragma unroll
    for (int nt = 0; nt < 8; ++nt) bb[nt] = b[nt * 16 + lm];
    __syncthreads();

    const int nbase = (blockIdx.x * 8 + wid) * 16;
    float s8[8], ss8[8];
    #pragma unroll
    for (int j = 0; j < 8; ++j) { s8[j] = 0.0f; ss8[j] = 0.0f; }

    if (nbase < NN) {                                   // wave-uniform guard (NN%16==0)
        int   ol = offs[nbase + (lane <= 16 ? lane : 16)];
        float dv = (lane < 16) ? dinv[nbase + lane] : 0.0f;
        const uint4* xn4 = (const uint4*)xn;

        // ---- phase 1: aggregate 16 nodes
        for (int r = 0; r < 16; ++r) {
            int beg = __shfl(ol, r);
            int n   = __shfl(ol, r + 1) - beg;
            float di = __shfl(dv, r);
            float acc[8];
            #pragma unroll
            for (int j = 0; j < 8; ++j) acc[j] = 0.0f;

            for (int base = 0; base < n; base += 64) {
                int m = n - base; if (m > 64) m = 64;
                int sidx = (lane < m) ? srcs[beg + base + lane] : 0;
                int iters = (m + 3) >> 2;
                for (int it2 = 0; it2 < iters; ++it2) {
                    int k = it2 * 4 + lk;
                    int srow = __shfl(sidx, k);         // shfl outside divergence
                    if (k < m) {
                        uint4 v = xn4[(size_t)srow * 16 + lm];
                        acc[0] += bflo(v.x); acc[1] += bfhi(v.x);
                        acc[2] += bflo(v.y); acc[3] += bfhi(v.y);
                        acc[4] += bflo(v.z); acc[5] += bfhi(v.z);
                        acc[6] += bflo(v.w); acc[7] += bfhi(v.w);
                    }
                }
            }
            #pragma unroll
            for (int j = 0; j < 8; ++j) {
                acc[j] += __shfl_xor(acc[j], 16);
                acc[j] += __shfl_xor(acc[j], 32);
            }
            if (lk == 0) {   // 16 lanes write the packed bf16 row (swizzled)
                unsigned p0 = ((unsigned)f2bf(acc[1] * di) << 16) | f2bf(acc[0] * di);
                unsigned p1 = ((unsigned)f2bf(acc[3] * di) << 16) | f2bf(acc[2] * di);
                unsigned p2 = ((unsigned)f2bf(acc[5] * di) << 16) | f2bf(acc[4] * di);
                unsigned p3 = ((unsigned)f2bf(acc[7] * di) << 16) | f2bf(acc[6] * di);
                *(uint4*)(agp + r * 256 + ((lm ^ (r & 7)) << 4)) = make_uint4(p0, p1, p2, p3);
            }
        }

        // ---- phase 2: out[16x128] = agg[16x128] @ W + b   (DS pipe is in-order per wave)
        f32x4 dacc[8];
        #pragma unroll
        for (int nt = 0; nt < 8; ++nt) dacc[nt] = (f32x4){0.f, 0.f, 0.f, 0.f};
        #pragma unroll
        for (int ks = 0; ks < 4; ++ks) {
            bf16x8 a = *(const bf16x8*)(agp + lm * 256 + ((ks * 64 + lk * 16) ^ ((lm & 7) << 4)));
            #pragma unroll
            for (int nt = 0; nt < 8; ++nt) {
                int brow = nt * 16 + lm;
                bf16x8 bfr = *(const bf16x8*)(Wl + brow * 256 + ((ks * 64 + lk * 16) ^ ((brow & 7) << 4)));
                dacc[nt] = __builtin_amdgcn_mfma_f32_16x16x32_bf16(a, bfr, dacc[nt], 0, 0, 0);
            }
        }
        // epilogue: D row = lk*4+r, col = nt*16+lm
        #pragma unroll
        for (int nt = 0; nt < 8; ++nt)
            #pragma unroll
            for (int r = 0; r < 4; ++r) {
                float val = dacc[nt][r] + bb[nt];
                out[(size_t)(nbase + lk * 4 + r) * DD + nt * 16 + lm] = val;
                s8[nt] += val; ss8[nt] += val * val;
            }
    }

    // ---- stats reduce: across lk groups, then across waves
    #pragma unroll
    for (int nt = 0; nt < 8; ++nt) {
        s8[nt]  += __shfl_xor(s8[nt], 16);  s8[nt]  += __shfl_xor(s8[nt], 32);
        ss8[nt] += __shfl_xor(ss8[nt], 16); ss8[nt] += __shfl_xor(ss8[nt], 32);
    }
    if (lk == 0) {
        #pragma unroll
        for (int nt = 0; nt < 8; ++nt) {
            lsum[wid][nt * 16 + lm] = s8[nt];
            lss[wid][nt * 16 + lm]  = ss8[nt];
        }
    }
    __syncthreads();
    if (tid < 128) {
        float a = 0.0f, c = 0.0f;
        #pragma unroll
        for (int w = 0; w < 8; ++w) { a += lsum[w][tid]; c += lss[w][tid]; }
        partial[(size_t)blockIdx.x * 256 + tid]       = a;
        partial[(size_t)blockIdx.x * 256 + 128 + tid] = c;
    }
}

// ---------------------------------------------------------------- reduce partials -> stats[256] (sums | sumsq)
__global__ __launch_bounds__(256) void k_red(const float* __restrict__ partial,
                                             float* __restrict__ stats) {
    int tid = threadIdx.x;
    float a = 0.0f;
    for (int r = blockIdx.x; r < NBLK; r += 64)
        a += partial[(size_t)r * 256 + tid];
    unsafeAtomicAdd(&stats[tid], a);
}

// ---------------------------------------------------------------- BN apply + ReLU + residual
__global__ __launch_bounds__(256) void k_final(float* __restrict__ out,
                                               const float* __restrict__ x,
                                               const float* __restrict__ gamma,
                                               const float* __restrict__ beta,
                                               const float* __restrict__ stats) {
    int idx = blockIdx.x * 256 + threadIdx.x;
    if (idx >= NN * DD / 4) return;
    int c4 = idx & 31;

    const float invN = 1.0f / (float)NN;
    float4 sm  = ((const float4*)stats)[c4];
    float4 sq  = ((const float4*)stats)[32 + c4];
    float4 g   = ((const float4*)gamma)[c4];
    float4 be  = ((const float4*)beta)[c4];
    float4 v   = ((float4*)out)[idx];
    float4 xr  = ((const float4*)x)[idx];

    float m0 = sm.x * invN, m1 = sm.y * invN, m2 = sm.z * invN, m3 = sm.w * invN;
    float r0 = rsqrtf(sq.x * invN - m0 * m0 + BN_EPS);
    float r1 = rsqrtf(sq.y * invN - m1 * m1 + BN_EPS);
    float r2 = rsqrtf(sq.z * invN - m2 * m2 + BN_EPS);
    float r3 = rsqrtf(sq.w * invN - m3 * m3 + BN_EPS);

    float4 o;
    o.x = fmaxf((v.x - m0) * r0 * g.x + be.x, 0.0f) + xr.x;
    o.y = fmaxf((v.y - m1) * r1 * g.y + be.y, 0.0f) + xr.y;
    o.z = fmaxf((v.z - m2) * r2 * g.z + be.z, 0.0f) + xr.z;
    o.w = fmaxf((v.w - m3) * r3 * g.w + be.w, 0.0f) + xr.w;
    ((float4*)out)[idx] = o;
}

// ---------------------------------------------------------------- launch
extern "C" void kernel_launch(void* const* d_in, const int* in_sizes, int n_in,
                              void* d_out, int out_size, void* d_ws, size_t ws_size,
                              hipStream_t stream) {
    const float* x     = (const float*)d_in[0];
    const int*   ei    = (const int*)d_in[1];    // [2, NE]
    const float* W     = (const float*)d_in[2];
    const float* b     = (const float*)d_in[3];
    const float* gamma = (const float*)d_in[4];
    const float* beta  = (const float*)d_in[5];
    float*       out   = (float*)d_out;

    char*  base = (char*)d_ws;
    size_t off  = 0;
    auto carve = [&](size_t bytes) -> void* {
        void* p = base + off;
        off = (off + bytes + 255) & ~(size_t)255;
        return p;
    };
    unsigned short* xn    = (unsigned short*)carve((size_t)NN * DD * 2);   // 25.6 MB
    float*          dinv  = (float*)carve((size_t)NN * 4);
    float*          stats = (float*)carve(256 * 4);
    int*            cnt   = (int*)carve((size_t)NN * 4);
    int*            offs  = (int*)carve((size_t)(NN + 1) * 4);
    int*            cur   = (int*)carve((size_t)NN * 4);
    int*            bsum  = (int*)carve(2048);
    int*            srcs  = (int*)carve((size_t)(NE + NN) * 4);            // 2.8 MB
    unsigned short* Wt    = (unsigned short*)carve(DD * DD * 2);
    float*          partial = (float*)carve((size_t)NBLK * 256 * 4);       // 0.8 MB

    const int* src = ei;        // edge_index[0]
    const int* dst = ei + NE;   // edge_index[1]

    k_init   <<<NB1, 256, 0, stream>>>(cnt, stats, W, Wt);
    k_count  <<<(NE + 255) / 256, 256, 0, stream>>>(dst, cnt);
    k_scan1  <<<NB1, 256, 0, stream>>>(cnt, offs, bsum);
    k_scan2  <<<1, 512, 0, stream>>>(bsum);
    k_scan3  <<<NB1, 256, 0, stream>>>(offs, bsum, cnt, cur, dinv, srcs);
    k_cvfill <<<NCV + NFB, 256, 0, stream>>>(x, dinv, xn, src, dst, cur, srcs);
    k_gather <<<NBLK, 512, 0, stream>>>(offs, srcs, xn, dinv, b, Wt, out, partial);
    k_red    <<<64, 256, 0, stream>>>(partial, stats);
    k_final  <<<(NN * DD / 4 + 255) / 256, 256, 0, stream>>>(out, x, gamma, beta, stats);
}

// Round 7
// 159.268 us; speedup vs baseline: 1.1966x; 1.1966x over previous
//
#include <hip/hip_runtime.h>

#define NN 100000
#define NE 600000
#define DD 128
#define BN_EPS 1e-5f
#define NB1 391                 // (NN+255)/256 scan blocks
#define NCV 12500               // convert blocks (8 rows each)
#define NFB 2344                // fill blocks
#define NBLK 1563               // gather blocks (256 thr, 4 waves, 64 nodes)

typedef __attribute__((ext_vector_type(8))) short bf16x8;
typedef __attribute__((ext_vector_type(4))) float f32x4;

static __device__ __forceinline__ unsigned short f2bf(float f) {
    unsigned u = __float_as_uint(f);
    unsigned r = (u + 0x7FFFu + ((u >> 16) & 1u)) >> 16;   // RNE
    return (unsigned short)r;
}
static __device__ __forceinline__ float bflo(unsigned v) { return __uint_as_float(v << 16); }
static __device__ __forceinline__ float bfhi(unsigned v) { return __uint_as_float(v & 0xFFFF0000u); }

// ---------------------------------------------------------------- init: cnt=0, stats=0, W->Wt bf16 transpose
__global__ __launch_bounds__(256) void k_init(int* __restrict__ cnt,
                                              float* __restrict__ stats,
                                              const float* __restrict__ W,
                                              unsigned short* __restrict__ Wt) {
    int i = blockIdx.x * 256 + threadIdx.x;
    if (i < NN) cnt[i] = 0;
    if (i < 256) stats[i] = 0.0f;
    if (i < DD * DD) {
        int k = i >> 7, c = i & 127;
        Wt[c * DD + k] = f2bf(W[i]);   // Wt[col][k]
    }
}

// ---------------------------------------------------------------- count incoming edges
__global__ __launch_bounds__(256) void k_count(const int* __restrict__ dst,
                                               int* __restrict__ cnt) {
    int e = blockIdx.x * 256 + threadIdx.x;
    if (e < NE) atomicAdd(&cnt[dst[e]], 1);
}

// ---------------------------------------------------------------- scan pass 1 over (cnt[i]+1)
__global__ __launch_bounds__(256) void k_scan1(const int* __restrict__ cnt,
                                               int* __restrict__ offs,
                                               int* __restrict__ bsum) {
    __shared__ int tmp[256];
    int tid = threadIdx.x;
    int i = blockIdx.x * 256 + tid;
    int v = (i < NN) ? (cnt[i] + 1) : 0;
    tmp[tid] = v;
    __syncthreads();
    #pragma unroll
    for (int d = 1; d < 256; d <<= 1) {
        int t = (tid >= d) ? tmp[tid - d] : 0;
        __syncthreads();
        tmp[tid] += t;
        __syncthreads();
    }
    if (i < NN) offs[i] = tmp[tid] - v;
    if (tid == 255) bsum[blockIdx.x] = tmp[255];
}

// ---------------------------------------------------------------- scan pass 2 (1 block)
__global__ __launch_bounds__(512) void k_scan2(int* __restrict__ bsum) {
    __shared__ int tmp[512];
    int tid = threadIdx.x;
    int v = (tid < NB1) ? bsum[tid] : 0;
    tmp[tid] = v;
    __syncthreads();
    #pragma unroll
    for (int d = 1; d < 512; d <<= 1) {
        int t = (tid >= d) ? tmp[tid - d] : 0;
        __syncthreads();
        tmp[tid] += t;
        __syncthreads();
    }
    if (tid < NB1) bsum[tid] = tmp[tid] - v;
}

// ---------------------------------------------------------------- scan pass 3
__global__ __launch_bounds__(256) void k_scan3(int* __restrict__ offs,
                                               const int* __restrict__ bsum,
                                               const int* __restrict__ cnt,
                                               int* __restrict__ cur,
                                               float* __restrict__ dinv,
                                               int* __restrict__ srcs) {
    int i = blockIdx.x * 256 + threadIdx.x;
    if (i < NN) {
        int o = offs[i] + bsum[blockIdx.x];
        offs[i] = o;
        dinv[i] = rsqrtf((float)(cnt[i] + 1));
        srcs[o] = i;                     // self edge at slot 0
        cur[i]  = o + 1;
        if (i == 0) offs[NN] = NE + NN;  // sentinel
    }
}

// ---------------------------------------------------------------- merged: CSR fill (FIRST) || xn = bf16(x*dinv)
// fill blocks lead the grid so their atomic latency overlaps the BW-bound convert.
__global__ __launch_bounds__(256) void k_cvfill(const float* __restrict__ x,
                                                const float* __restrict__ dinv,
                                                unsigned short* __restrict__ xn,
                                                const int* __restrict__ src,
                                                const int* __restrict__ dst,
                                                int* __restrict__ cur,
                                                int* __restrict__ srcs) {
    int bid = blockIdx.x;
    if (bid < NFB) {
        int e = bid * 256 + threadIdx.x;
        if (e < NE) {
            int s = src[e], t = dst[e];
            int slot = atomicAdd(&cur[t], 1);
            srcs[slot] = s;
        }
    } else {
        int r  = (bid - NFB) * 8 + (threadIdx.x >> 5);
        int c4 = threadIdx.x & 31;
        float di = dinv[r];
        float4 v = ((const float4*)x)[(size_t)r * 32 + c4];
        unsigned p0 = ((unsigned)f2bf(v.y * di) << 16) | f2bf(v.x * di);
        unsigned p1 = ((unsigned)f2bf(v.w * di) << 16) | f2bf(v.z * di);
        ((uint2*)xn)[(size_t)r * 32 + c4] = make_uint2(p0, p1);
    }
}

// ---------------------------------------------------------------- fused gather + MFMA-GEMM + bias + stats
// 256 threads = 4 waves; wave owns 16 nodes. Lane (lm,lk) walks node (nbase+lm)'s
// edge list, accumulating its A-fragment k-slice in registers. No agg LDS.
__global__ __launch_bounds__(256) void k_gather(const int* __restrict__ offs,
                                                const int* __restrict__ srcs,
                                                const unsigned short* __restrict__ xn,
                                                const float* __restrict__ dinv,
                                                const float* __restrict__ b,
                                                const unsigned short* __restrict__ Wt,
                                                float* __restrict__ out,
                                                float* __restrict__ partial) {
    __shared__ uint4 Wl4[2048];                   // 32 KB swizzled W
    __shared__ float lsum[4][128], lss[4][128];   // 4 KB stats
    const int tid  = threadIdx.x;
    const int wid  = tid >> 6;
    const int lane = tid & 63;
    const int lm   = lane & 15;       // node-row within wave tile / A-row / B-col
    const int lk   = lane >> 4;       // k-chunk 0..3
    char* Wl = (char*)Wl4;

    // stage W: swizzle byte(row, c16) = row*256 + ((c16 ^ (row&7)) << 4)
    #pragma unroll
    for (int it = 0; it < 8; ++it) {
        int chunk = it * 256 + tid;            // 0..2047
        int row = chunk >> 4, c16 = chunk & 15;
        uint4 v = *(const uint4*)(Wt + row * DD + c16 * 8);
        *(uint4*)(Wl + row * 256 + ((c16 ^ (row & 7)) << 4)) = v;
    }
    float bb[8];
    #pragma unroll
    for (int nt = 0; nt < 8; ++nt) bb[nt] = b[nt * 16 + lm];
    __syncthreads();

    const int nbase = (blockIdx.x * 4 + wid) * 16;
    float s8[8], ss8[8];
    #pragma unroll
    for (int j = 0; j < 8; ++j) { s8[j] = 0.0f; ss8[j] = 0.0f; }

    if (nbase < NN) {                          // wave-uniform (NN % 16 == 0)
        int   ol = offs[nbase + (lane <= 16 ? lane : 16)];
        float dv = (lane < 16) ? dinv[nbase + lane] : 0.0f;
        int   beg = __shfl(ol, lm);
        int   n   = __shfl(ol, lm + 1) - beg;
        float di  = __shfl(dv, lm);
        const uint4* xn4 = (const uint4*)xn;

        float acc[4][8];
        #pragma unroll
        for (int ks = 0; ks < 4; ++ks)
            #pragma unroll
            for (int j = 0; j < 8; ++j) acc[ks][j] = 0.0f;

        int k = 0;
        for (; k + 2 <= n; k += 2) {           // 2 edges in flight -> 8 loads deep
            int s0 = srcs[beg + k];
            int s1 = srcs[beg + k + 1];
            uint4 v0[4], v1[4];
            #pragma unroll
            for (int ks = 0; ks < 4; ++ks) v0[ks] = xn4[(size_t)s0 * 16 + ks * 4 + lk];
            #pragma unroll
            for (int ks = 0; ks < 4; ++ks) v1[ks] = xn4[(size_t)s1 * 16 + ks * 4 + lk];
            #pragma unroll
            for (int ks = 0; ks < 4; ++ks) {
                acc[ks][0] += bflo(v0[ks].x) + bflo(v1[ks].x);
                acc[ks][1] += bfhi(v0[ks].x) + bfhi(v1[ks].x);
                acc[ks][2] += bflo(v0[ks].y) + bflo(v1[ks].y);
                acc[ks][3] += bfhi(v0[ks].y) + bfhi(v1[ks].y);
                acc[ks][4] += bflo(v0[ks].z) + bflo(v1[ks].z);
                acc[ks][5] += bfhi(v0[ks].z) + bfhi(v1[ks].z);
                acc[ks][6] += bflo(v0[ks].w) + bflo(v1[ks].w);
                acc[ks][7] += bfhi(v0[ks].w) + bfhi(v1[ks].w);
            }
        }
        if (k < n) {
            int s0 = srcs[beg + k];
            #pragma unroll
            for (int ks = 0; ks < 4; ++ks) {
                uint4 v = xn4[(size_t)s0 * 16 + ks * 4 + lk];
                acc[ks][0] += bflo(v.x); acc[ks][1] += bfhi(v.x);
                acc[ks][2] += bflo(v.y); acc[ks][3] += bfhi(v.y);
                acc[ks][4] += bflo(v.z); acc[ks][5] += bfhi(v.z);
                acc[ks][6] += bflo(v.w); acc[ks][7] += bfhi(v.w);
            }
        }

        // scale by dinv[node] and convert to A-fragments
        bf16x8 a[4];
        #pragma unroll
        for (int ks = 0; ks < 4; ++ks)
            #pragma unroll
            for (int j = 0; j < 8; ++j) a[ks][j] = (short)f2bf(acc[ks][j] * di);

        // MFMA vs LDS-staged W
        f32x4 dacc[8];
        #pragma unroll
        for (int nt = 0; nt < 8; ++nt) dacc[nt] = (f32x4){0.f, 0.f, 0.f, 0.f};
        #pragma unroll
        for (int ks = 0; ks < 4; ++ks)
            #pragma unroll
            for (int nt = 0; nt < 8; ++nt) {
                int brow = nt * 16 + lm;
                bf16x8 bfr = *(const bf16x8*)(Wl + brow * 256 + ((ks * 64 + lk * 16) ^ ((brow & 7) << 4)));
                dacc[nt] = __builtin_amdgcn_mfma_f32_16x16x32_bf16(a[ks], bfr, dacc[nt], 0, 0, 0);
            }

        // epilogue: D row = lk*4+r, col = nt*16+lm
        #pragma unroll
        for (int nt = 0; nt < 8; ++nt)
            #pragma unroll
            for (int r = 0; r < 4; ++r) {
                float val = dacc[nt][r] + bb[nt];
                out[(size_t)(nbase + lk * 4 + r) * DD + nt * 16 + lm] = val;
                s8[nt] += val; ss8[nt] += val * val;
            }
    }

    // stats: reduce across lk groups, stash per wave, then cross-wave
    #pragma unroll
    for (int nt = 0; nt < 8; ++nt) {
        s8[nt]  += __shfl_xor(s8[nt], 16);  s8[nt]  += __shfl_xor(s8[nt], 32);
        ss8[nt] += __shfl_xor(ss8[nt], 16); ss8[nt] += __shfl_xor(ss8[nt], 32);
    }
    if (lk == 0) {
        #pragma unroll
        for (int nt = 0; nt < 8; ++nt) {
            lsum[wid][nt * 16 + lm] = s8[nt];
            lss[wid][nt * 16 + lm]  = ss8[nt];
        }
    }
    __syncthreads();
    if (tid < 128) {
        float a = lsum[0][tid] + lsum[1][tid] + lsum[2][tid] + lsum[3][tid];
        float c = lss[0][tid]  + lss[1][tid]  + lss[2][tid]  + lss[3][tid];
        partial[(size_t)blockIdx.x * 256 + tid]       = a;
        partial[(size_t)blockIdx.x * 256 + 128 + tid] = c;
    }
}

// ---------------------------------------------------------------- reduce partials -> stats[256]
__global__ __launch_bounds__(256) void k_red(const float* __restrict__ partial,
                                             float* __restrict__ stats) {
    int tid = threadIdx.x;
    float a = 0.0f;
    for (int r = blockIdx.x; r < NBLK; r += 64)
        a += partial[(size_t)r * 256 + tid];
    unsafeAtomicAdd(&stats[tid], a);
}

// ---------------------------------------------------------------- BN apply + ReLU + residual
__global__ __launch_bounds__(256) void k_final(float* __restrict__ out,
                                               const float* __restrict__ x,
                                               const float* __restrict__ gamma,
                                               const float* __restrict__ beta,
                                               const float* __restrict__ stats) {
    int idx = blockIdx.x * 256 + threadIdx.x;
    if (idx >= NN * DD / 4) return;
    int c4 = idx & 31;

    const float invN = 1.0f / (float)NN;
    float4 sm  = ((const float4*)stats)[c4];
    float4 sq  = ((const float4*)stats)[32 + c4];
    float4 g   = ((const float4*)gamma)[c4];
    float4 be  = ((const float4*)beta)[c4];
    float4 v   = ((float4*)out)[idx];
    float4 xr  = ((const float4*)x)[idx];

    float m0 = sm.x * invN, m1 = sm.y * invN, m2 = sm.z * invN, m3 = sm.w * invN;
    float r0 = rsqrtf(sq.x * invN - m0 * m0 + BN_EPS);
    float r1 = rsqrtf(sq.y * invN - m1 * m1 + BN_EPS);
    float r2 = rsqrtf(sq.z * invN - m2 * m2 + BN_EPS);
    float r3 = rsqrtf(sq.w * invN - m3 * m3 + BN_EPS);

    float4 o;
    o.x = fmaxf((v.x - m0) * r0 * g.x + be.x, 0.0f) + xr.x;
    o.y = fmaxf((v.y - m1) * r1 * g.y + be.y, 0.0f) + xr.y;
    o.z = fmaxf((v.z - m2) * r2 * g.z + be.z, 0.0f) + xr.z;
    o.w = fmaxf((v.w - m3) * r3 * g.w + be.w, 0.0f) + xr.w;
    ((float4*)out)[idx] = o;
}

// ---------------------------------------------------------------- launch
extern "C" void kernel_launch(void* const* d_in, const int* in_sizes, int n_in,
                              void* d_out, int out_size, void* d_ws, size_t ws_size,
                              hipStream_t stream) {
    const float* x     = (const float*)d_in[0];
    const int*   ei    = (const int*)d_in[1];    // [2, NE]
    const float* W     = (const float*)d_in[2];
    const float* b     = (const float*)d_in[3];
    const float* gamma = (const float*)d_in[4];
    const float* beta  = (const float*)d_in[5];
    float*       out   = (float*)d_out;

    char*  base = (char*)d_ws;
    size_t off  = 0;
    auto carve = [&](size_t bytes) -> void* {
        void* p = base + off;
        off = (off + bytes + 255) & ~(size_t)255;
        return p;
    };
    unsigned short* xn    = (unsigned short*)carve((size_t)NN * DD * 2);   // 25.6 MB
    float*          dinv  = (float*)carve((size_t)NN * 4);
    float*          stats = (float*)carve(256 * 4);
    int*            cnt   = (int*)carve((size_t)NN * 4);
    int*            offs  = (int*)carve((size_t)(NN + 1) * 4);
    int*            cur   = (int*)carve((size_t)NN * 4);
    int*            bsum  = (int*)carve(2048);
    int*            srcs  = (int*)carve((size_t)(NE + NN) * 4);            // 2.8 MB
    unsigned short* Wt    = (unsigned short*)carve(DD * DD * 2);
    float*          partial = (float*)carve((size_t)NBLK * 256 * 4);       // 1.6 MB

    const int* src = ei;        // edge_index[0]
    const int* dst = ei + NE;   // edge_index[1]

    k_init   <<<NB1, 256, 0, stream>>>(cnt, stats, W, Wt);
    k_count  <<<(NE + 255) / 256, 256, 0, stream>>>(dst, cnt);
    k_scan1  <<<NB1, 256, 0, stream>>>(cnt, offs, bsum);
    k_scan2  <<<1, 512, 0, stream>>>(bsum);
    k_scan3  <<<NB1, 256, 0, stream>>>(offs, bsum, cnt, cur, dinv, srcs);
    k_cvfill <<<NFB + NCV, 256, 0, stream>>>(x, dinv, xn, src, dst, cur, srcs);
    k_gather <<<NBLK, 256, 0, stream>>>(offs, srcs, xn, dinv, b, Wt, out, partial);
    k_red    <<<64, 256, 0, stream>>>(partial, stats);
    k_final  <<<(NN * DD / 4 + 255) / 256, 256, 0, stream>>>(out, x, gamma, beta, stats);
}